// Round 1
// 62.449 us; speedup vs baseline: 1.0330x; 1.0330x over previous
//
#include <hip/hip_runtime.h>
#include <math.h>

// Fixed-size problem: x(12), K(4x4), b(4), G(4x4), adj(4x4) -> out(12), all fp32.
// Single-wave kernel, lane 0 computes everything serially in registers.
//
// This revision minimizes the serial critical path:
//  - float4 vector loads (14 dwordx4 instead of ~53 dword loads)
//  - 6 unique __cosf (v_cos_f32) instead of 16 libm cosf (cos(aj-ai) is
//    symmetric; diagonal terms vanish because (v_j - v_j) == 0)
//  - tanh via v_exp_f32: tanh(x) = 1 - 2/(exp(2x)+1)  (~1e-6 rel err,
//    tolerance is 4.8e-2)
// Dominant eigenvalue of M = G*G^T via power iteration (Perron-Frobenius:
// M entrywise positive -> all-ones start converges geometrically). Final
// Rayleigh quotient folded into the last iteration.

__device__ __forceinline__ float fast_tanh(float s) {
    float e = __expf(2.0f * s);             // v_exp_f32 path
    return 1.0f - __fdividef(2.0f, e + 1.0f);
}

__global__ void kuramoto_kernel(const float* __restrict__ x,
                                const float* __restrict__ K,
                                const float* __restrict__ b,
                                const float* __restrict__ G,
                                const float* __restrict__ adj,
                                float* __restrict__ out) {
    if (threadIdx.x != 0) return;

    // ---- vectorized loads, all issued up front ----
    const float4* x4   = reinterpret_cast<const float4*>(x);
    const float4* K4   = reinterpret_cast<const float4*>(K);
    const float4* G4   = reinterpret_cast<const float4*>(G);
    const float4* A4   = reinterpret_cast<const float4*>(adj);
    const float4* b4   = reinterpret_cast<const float4*>(b);

    float4 va  = x4[0];
    float4 vv  = x4[1];
    float4 vxi = x4[2];
    float4 kr0 = K4[0], kr1 = K4[1], kr2 = K4[2], kr3 = K4[3];
    float4 gr0 = G4[0], gr1 = G4[1], gr2 = G4[2], gr3 = G4[3];
    float4 ar0 = A4[0], ar1 = A4[1], ar2 = A4[2], ar3 = A4[3];
    float4 vb  = b4[0];

    float a[4]  = { va.x, va.y, va.z, va.w };
    float v[4]  = { vv.x, vv.y, vv.z, vv.w };
    float xi[4] = { vxi.x, vxi.y, vxi.z, vxi.w };
    float br[4] = { vb.x, vb.y, vb.z, vb.w };
    float Kr[16] = { kr0.x,kr0.y,kr0.z,kr0.w, kr1.x,kr1.y,kr1.z,kr1.w,
                     kr2.x,kr2.y,kr2.z,kr2.w, kr3.x,kr3.y,kr3.z,kr3.w };
    float Gr[16] = { gr0.x,gr0.y,gr0.z,gr0.w, gr1.x,gr1.y,gr1.z,gr1.w,
                     gr2.x,gr2.y,gr2.z,gr2.w, gr3.x,gr3.y,gr3.z,gr3.w };
    float adjr[16] = { ar0.x,ar0.y,ar0.z,ar0.w, ar1.x,ar1.y,ar1.z,ar1.w,
                       ar2.x,ar2.y,ar2.z,ar2.w, ar3.x,ar3.y,ar3.z,ar3.w };

    // th = tanh(K @ xi + b)
    float th[4];
    #pragma unroll
    for (int i = 0; i < 4; ++i) {
        float s = br[i];
        #pragma unroll
        for (int j = 0; j < 4; ++j) s += Kr[i * 4 + j] * xi[j];
        th[i] = fast_tanh(s);
    }

    // dH = K^T @ th
    float dH[4];
    #pragma unroll
    for (int j = 0; j < 4; ++j) {
        float s = 0.0f;
        #pragma unroll
        for (int i = 0; i < 4; ++i) s += Kr[i * 4 + j] * th[i];
        dH[j] = s;
    }

    // Unique cosines: c[i][j] = cos(a[j]-a[i]) = c[j][i]; diagonal never used
    // because the (v_j - v_i) factor is zero there.
    float c[4][4];
    c[0][1] = c[1][0] = __cosf(a[1] - a[0]);
    c[0][2] = c[2][0] = __cosf(a[2] - a[0]);
    c[0][3] = c[3][0] = __cosf(a[3] - a[0]);
    c[1][2] = c[2][1] = __cosf(a[2] - a[1]);
    c[1][3] = c[3][1] = __cosf(a[3] - a[1]);
    c[2][3] = c[3][2] = __cosf(a[3] - a[2]);

    // interactions[j] = sum_{i != j} adj[i][j] * cos(a[j]-a[i]) * (v[j]-v[i])
    float inter[4];
    #pragma unroll
    for (int j = 0; j < 4; ++j) {
        float s = 0.0f;
        #pragma unroll
        for (int i = 0; i < 4; ++i) {
            if (i != j)
                s += adjr[i * 4 + j] * c[i][j] * (v[j] - v[i]);
        }
        inter[j] = s;
    }

    // u = -(adj .* G)^T @ dH  ->  u[j] = -sum_i adj[i][j]*G[i][j]*dH[i]
    float u[4];
    #pragma unroll
    for (int j = 0; j < 4; ++j) {
        float s = 0.0f;
        #pragma unroll
        for (int i = 0; i < 4; ++i) s += adjr[i * 4 + j] * Gr[i * 4 + j] * dH[i];
        u[j] = -s;
    }

    // M = G @ G^T (symmetric, entrywise positive)
    float M[16];
    #pragma unroll
    for (int i = 0; i < 4; ++i) {
        #pragma unroll
        for (int j = 0; j <= i; ++j) {
            float s = 0.0f;
            #pragma unroll
            for (int k = 0; k < 4; ++k) s += Gr[i * 4 + k] * Gr[j * 4 + k];
            M[i * 4 + j] = s;
            M[j * 4 + i] = s;
        }
    }

    // Power iteration; last pass yields lam = pv^T M pv with pv unit-norm.
    float pv[4] = {1.0f, 1.0f, 1.0f, 1.0f};
    float lam = 0.0f;
    #pragma unroll
    for (int it = 0; it < 12; ++it) {
        float w[4];
        #pragma unroll
        for (int i = 0; i < 4; ++i) {
            float s = 0.0f;
            #pragma unroll
            for (int j = 0; j < 4; ++j) s += M[i * 4 + j] * pv[j];
            w[i] = s;
        }
        if (it == 11) {
            lam = pv[0]*w[0] + pv[1]*w[1] + pv[2]*w[2] + pv[3]*w[3];
        } else {
            float n2 = w[0]*w[0] + w[1]*w[1] + w[2]*w[2] + w[3]*w[3];
            float inv = rsqrtf(n2);
            #pragma unroll
            for (int i = 0; i < 4; ++i) pv[i] = w[i] * inv;
        }
    }
    float gamma = 0.1f * lam;

    // J @ dH with J = [[0,-1,0,0],[1,0,0,0],[0,0,0,-1],[0,0,1,0]]
    float JdH[4] = { -dH[1], dH[0], -dH[3], dH[2] };

    // dxi_dt = (J - gamma*I) @ dH + (adj .* G) @ x2
    float dxi[4];
    #pragma unroll
    for (int i = 0; i < 4; ++i) {
        float s = JdH[i] - gamma * dH[i];
        #pragma unroll
        for (int j = 0; j < 4; ++j) s += adjr[i * 4 + j] * Gr[i * 4 + j] * v[j];
        dxi[i] = s;
    }

    // out = concat(x2, 1.25*u*inter, dxi)
    #pragma unroll
    for (int i = 0; i < 4; ++i) {
        out[i]     = v[i];
        out[4 + i] = 1.25f * u[i] * inter[i];
        out[8 + i] = dxi[i];
    }
}

extern "C" void kernel_launch(void* const* d_in, const int* in_sizes, int n_in,
                              void* d_out, int out_size, void* d_ws, size_t ws_size,
                              hipStream_t stream) {
    // inputs: 0=t(1), 1=x(12), 2=K(16), 3=b(4), 4=G(16), 5=adj(16) — all fp32
    const float* x   = (const float*)d_in[1];
    const float* K   = (const float*)d_in[2];
    const float* b   = (const float*)d_in[3];
    const float* G   = (const float*)d_in[4];
    const float* adj = (const float*)d_in[5];
    float* out = (float*)d_out;

    kuramoto_kernel<<<dim3(1), dim3(64), 0, stream>>>(x, K, b, G, adj, out);
}

// Round 2
// 61.766 us; speedup vs baseline: 1.0444x; 1.0111x over previous
//
#include <hip/hip_runtime.h>
#include <math.h>

// Fixed-size problem: x(12), K(4x4), b(4), G(4x4), adj(4x4) -> out(12), all fp32.
// Single-wave kernel, lane 0 computes everything serially in registers.
//
// Cost model (measured r0->r1): one wave, one active lane => ~1.5 ns per
// instruction on the serial chain. This revision removes ~200 instructions:
//  - power iteration: 12 normalized iters -> 5 UNNORMALIZED matvecs.
//    fp32 headroom: lam1(G G^T) <= ~8 for G~U[0,1]^{4x4}, so |w5| < ~1e5,
//    dots < ~1e9 — no overflow, all 11 rsqrt+rescale steps deleted.
//    Rayleigh error ~ (lam2/lam1)^8 <= 7e-5 rel even at gap 0.3 (actual gap
//    for near-rank-1 GG^T is far smaller); output tolerance is 4.8e-2.
//  - output: 3x global_store_dwordx4 instead of 12 scalar stores.
// Retained from r1: float4 loads, 6 unique __cosf (symmetry + zero diagonal),
// tanh(x) = 1 - 2/(exp(2x)+1) via v_exp_f32.

__device__ __forceinline__ float fast_tanh(float s) {
    float e = __expf(2.0f * s);             // v_exp_f32 path
    return 1.0f - __fdividef(2.0f, e + 1.0f);
}

__global__ void kuramoto_kernel(const float* __restrict__ x,
                                const float* __restrict__ K,
                                const float* __restrict__ b,
                                const float* __restrict__ G,
                                const float* __restrict__ adj,
                                float* __restrict__ out) {
    if (threadIdx.x != 0) return;

    // ---- vectorized loads, all issued up front ----
    const float4* x4   = reinterpret_cast<const float4*>(x);
    const float4* K4   = reinterpret_cast<const float4*>(K);
    const float4* G4   = reinterpret_cast<const float4*>(G);
    const float4* A4   = reinterpret_cast<const float4*>(adj);
    const float4* b4   = reinterpret_cast<const float4*>(b);

    float4 va  = x4[0];
    float4 vv  = x4[1];
    float4 vxi = x4[2];
    float4 kr0 = K4[0], kr1 = K4[1], kr2 = K4[2], kr3 = K4[3];
    float4 gr0 = G4[0], gr1 = G4[1], gr2 = G4[2], gr3 = G4[3];
    float4 ar0 = A4[0], ar1 = A4[1], ar2 = A4[2], ar3 = A4[3];
    float4 vb  = b4[0];

    float a[4]  = { va.x, va.y, va.z, va.w };
    float v[4]  = { vv.x, vv.y, vv.z, vv.w };
    float xi[4] = { vxi.x, vxi.y, vxi.z, vxi.w };
    float br[4] = { vb.x, vb.y, vb.z, vb.w };
    float Kr[16] = { kr0.x,kr0.y,kr0.z,kr0.w, kr1.x,kr1.y,kr1.z,kr1.w,
                     kr2.x,kr2.y,kr2.z,kr2.w, kr3.x,kr3.y,kr3.z,kr3.w };
    float Gr[16] = { gr0.x,gr0.y,gr0.z,gr0.w, gr1.x,gr1.y,gr1.z,gr1.w,
                     gr2.x,gr2.y,gr2.z,gr2.w, gr3.x,gr3.y,gr3.z,gr3.w };
    float adjr[16] = { ar0.x,ar0.y,ar0.z,ar0.w, ar1.x,ar1.y,ar1.z,ar1.w,
                       ar2.x,ar2.y,ar2.z,ar2.w, ar3.x,ar3.y,ar3.z,ar3.w };

    // th = tanh(K @ xi + b)
    float th[4];
    #pragma unroll
    for (int i = 0; i < 4; ++i) {
        float s = br[i];
        #pragma unroll
        for (int j = 0; j < 4; ++j) s += Kr[i * 4 + j] * xi[j];
        th[i] = fast_tanh(s);
    }

    // dH = K^T @ th
    float dH[4];
    #pragma unroll
    for (int j = 0; j < 4; ++j) {
        float s = 0.0f;
        #pragma unroll
        for (int i = 0; i < 4; ++i) s += Kr[i * 4 + j] * th[i];
        dH[j] = s;
    }

    // Unique cosines: c[i][j] = cos(a[j]-a[i]) = c[j][i]; diagonal never used
    // because the (v_j - v_i) factor is zero there.
    float c[4][4];
    c[0][1] = c[1][0] = __cosf(a[1] - a[0]);
    c[0][2] = c[2][0] = __cosf(a[2] - a[0]);
    c[0][3] = c[3][0] = __cosf(a[3] - a[0]);
    c[1][2] = c[2][1] = __cosf(a[2] - a[1]);
    c[1][3] = c[3][1] = __cosf(a[3] - a[1]);
    c[2][3] = c[3][2] = __cosf(a[3] - a[2]);

    // interactions[j] = sum_{i != j} adj[i][j] * cos(a[j]-a[i]) * (v[j]-v[i])
    float inter[4];
    #pragma unroll
    for (int j = 0; j < 4; ++j) {
        float s = 0.0f;
        #pragma unroll
        for (int i = 0; i < 4; ++i) {
            if (i != j)
                s += adjr[i * 4 + j] * c[i][j] * (v[j] - v[i]);
        }
        inter[j] = s;
    }

    // u = -(adj .* G)^T @ dH  ->  u[j] = -sum_i adj[i][j]*G[i][j]*dH[i]
    float u[4];
    #pragma unroll
    for (int j = 0; j < 4; ++j) {
        float s = 0.0f;
        #pragma unroll
        for (int i = 0; i < 4; ++i) s += adjr[i * 4 + j] * Gr[i * 4 + j] * dH[i];
        u[j] = -s;
    }

    // M = G @ G^T (symmetric, entrywise positive)
    float M[16];
    #pragma unroll
    for (int i = 0; i < 4; ++i) {
        #pragma unroll
        for (int j = 0; j <= i; ++j) {
            float s = 0.0f;
            #pragma unroll
            for (int k = 0; k < 4; ++k) s += Gr[i * 4 + k] * Gr[j * 4 + k];
            M[i * 4 + j] = s;
            M[j * 4 + i] = s;
        }
    }

    // Unnormalized power iteration: w1 = M.1 (row sums), w_{k+1} = M w_k.
    // lam = Rayleigh(w4) = (w4 . M w4)/(w4 . w4) = (w4.w5)/(w4.w4).
    float w1[4], w2[4], w3[4], w4[4], w5[4];
    #pragma unroll
    for (int i = 0; i < 4; ++i)
        w1[i] = M[i*4+0] + M[i*4+1] + M[i*4+2] + M[i*4+3];

    #pragma unroll
    for (int i = 0; i < 4; ++i) {
        float s = 0.0f;
        #pragma unroll
        for (int j = 0; j < 4; ++j) s += M[i*4+j] * w1[j];
        w2[i] = s;
    }
    #pragma unroll
    for (int i = 0; i < 4; ++i) {
        float s = 0.0f;
        #pragma unroll
        for (int j = 0; j < 4; ++j) s += M[i*4+j] * w2[j];
        w3[i] = s;
    }
    #pragma unroll
    for (int i = 0; i < 4; ++i) {
        float s = 0.0f;
        #pragma unroll
        for (int j = 0; j < 4; ++j) s += M[i*4+j] * w3[j];
        w4[i] = s;
    }
    #pragma unroll
    for (int i = 0; i < 4; ++i) {
        float s = 0.0f;
        #pragma unroll
        for (int j = 0; j < 4; ++j) s += M[i*4+j] * w4[j];
        w5[i] = s;
    }
    float num = w4[0]*w5[0] + w4[1]*w5[1] + w4[2]*w5[2] + w4[3]*w5[3];
    float den = w4[0]*w4[0] + w4[1]*w4[1] + w4[2]*w4[2] + w4[3]*w4[3];
    float gamma = 0.1f * __fdividef(num, den);

    // J @ dH with J = [[0,-1,0,0],[1,0,0,0],[0,0,0,-1],[0,0,1,0]]
    float JdH[4] = { -dH[1], dH[0], -dH[3], dH[2] };

    // dxi_dt = (J - gamma*I) @ dH + (adj .* G) @ x2
    float dxi[4];
    #pragma unroll
    for (int i = 0; i < 4; ++i) {
        float s = JdH[i] - gamma * dH[i];
        #pragma unroll
        for (int j = 0; j < 4; ++j) s += adjr[i * 4 + j] * Gr[i * 4 + j] * v[j];
        dxi[i] = s;
    }

    // out = concat(x2, 1.25*u*inter, dxi) — three dwordx4 stores.
    float4* out4 = reinterpret_cast<float4*>(out);
    out4[0] = make_float4(v[0], v[1], v[2], v[3]);
    out4[1] = make_float4(1.25f * u[0] * inter[0], 1.25f * u[1] * inter[1],
                          1.25f * u[2] * inter[2], 1.25f * u[3] * inter[3]);
    out4[2] = make_float4(dxi[0], dxi[1], dxi[2], dxi[3]);
}

extern "C" void kernel_launch(void* const* d_in, const int* in_sizes, int n_in,
                              void* d_out, int out_size, void* d_ws, size_t ws_size,
                              hipStream_t stream) {
    // inputs: 0=t(1), 1=x(12), 2=K(16), 3=b(4), 4=G(16), 5=adj(16) — all fp32
    const float* x   = (const float*)d_in[1];
    const float* K   = (const float*)d_in[2];
    const float* b   = (const float*)d_in[3];
    const float* G   = (const float*)d_in[4];
    const float* adj = (const float*)d_in[5];
    float* out = (float*)d_out;

    kuramoto_kernel<<<dim3(1), dim3(64), 0, stream>>>(x, K, b, G, adj, out);
}